// Round 11
// baseline (159.361 us; speedup 1.0000x reference)
//
#include <hip/hip_runtime.h>
#include <math.h>

// B=4, N=128, H=W=32, C=64.  out[b][j][n] = sigmoid(wl[j,:] . mean_hw MLP(...) + bl[j])
//
// R11: 32x32x16 MFMA, ACTS STAY IN REGISTERS (no LDS act round-trip).
// R8-R10 post-mortem: the 16x16 structure plateaus ~37us — serial per-layer
// LDS write->read chain + af re-reads, boxed in by the immovable 128-VGPR
// wall. New structure, per wave = 32 px column block:
//   D[o][p] = W.X: M=64 (2 mt of 32), N=32 px, K=64 (4 ks of 16).
//   C layout: col=lane&31, row=(reg&3)+8*(reg>>2)+4*(lane>>5)  [m74/m101]
//   B layout: n=lane&31, k=(lane>>5)*8+j  (analog of m120-verified 16x16x32)
//   Same col mapping => C->B transform = per ks: keep 4 regs, swap 4 with
//   lane^32 via ds_bpermute (derivation checked on concrete lanes):
//     h=0 lane: j0..3 = own r[8(ks&1)+j],   j4..7 = partner r[8(ks&1)+j-4]
//     h=1 lane: j0..3 = partner r[8(ks&1)+4+j], j4..7 = own r[8(ks&1)+4+j-4]
//   (mt = ks>>1). Exchange: send = h ? lo : hi; recv = bperm(lane^32).
// Bias: L1 folded into K=16 pad (a1 j=7 = b1, bft j=7 = 1). L2-5 via 2
// bias-outer MFMAs (biasA k=0 x ones-B k=0) instead of 8 b128 bias reads.
// Weights (32 A-frags, 32KB) in LDS lane-major; af reads have NO dependency
// on acts -> fully prefetchable. Pool accumulates in C-layout regs, flushed
// once via LDS atomicAdd into PO[64][36] (row pad 36 -> aligned + bank-spread).
// Tripwires: WRITE_SIZE ~48B (live ~118 regs, borderline); absmax (layout).

typedef float  f32x4  __attribute__((ext_vector_type(4)));
typedef float  f32x16 __attribute__((ext_vector_type(16)));
typedef f32x4  f32x4a __attribute__((may_alias));
typedef __bf16 bf16x8 __attribute__((ext_vector_type(8)));
typedef bf16x8 bf16x8a __attribute__((may_alias));
typedef __bf16 bf16x2 __attribute__((ext_vector_type(2)));
typedef unsigned int u32;
typedef u32 u32x4 __attribute__((ext_vector_type(4)));

#define MFMA32(a, b, c) __builtin_amdgcn_mfma_f32_32x32x16_bf16((a), (b), (c), 0, 0, 0)

__device__ __forceinline__ float lrelu(float x) { return fmaxf(x, 0.1f * x); }
__device__ __forceinline__ u32 pk2(float a, float b) {
    bf16x2 v; v[0] = (__bf16)a; v[1] = (__bf16)b;
    return __builtin_bit_cast(u32, v);
}
__device__ __forceinline__ f32x16 zero16() {
    f32x16 z;
    #pragma unroll
    for (int i = 0; i < 16; ++i) z[i] = 0.0f;
    return z;
}

__global__ __launch_bounds__(512, 2) void mlp_mfma_kernel(
    const float* __restrict__ image,   // [4,3,32,32]
    const float* __restrict__ coords,  // [4,128,2]
    const float* __restrict__ w1, const float* __restrict__ b1,   // [64,7],[64]
    const float* __restrict__ w2, const float* __restrict__ b2,   // [64,64],[64]
    const float* __restrict__ w3, const float* __restrict__ b3,
    const float* __restrict__ w4, const float* __restrict__ b4,
    const float* __restrict__ w5, const float* __restrict__ b5,
    const float* __restrict__ wl, const float* __restrict__ bl,   // [3,64],[3]
    float* __restrict__ out)           // [4,3,128]
{
    __shared__ __align__(16) __bf16 WF[32 * 512];   // 32 A-frags, lane-major (32 KB)
    __shared__ __align__(16) float  PO[64 * 36];    // pooled [ch][col] padded (9 KB)

    const int tid  = threadIdx.x;
    const int wave = tid >> 6;      // 0..7
    const int lane = tid & 63;
    const int col  = lane & 31;     // px-within-tile / out-ch col
    const int h1   = lane >> 5;     // 0/1 half
    const float hm = h1 ? 0.0f : 1.0f;
    const int bn   = blockIdx.x;
    const int b    = bn >> 7;

    // ---- zero pool scratch
    for (int i = tid; i < 64 * 36; i += 512) PO[i] = 0.0f;

    // ---- stage W2..W5 A-frags into LDS: frag id = l*8 + mt*4 + ks
    //      A[m=32mt+col][k=16ks+8h1+j] ; lane-major store
    {
        const float* Ws[4] = {w2, w3, w4, w5};
        #pragma unroll
        for (int i = 0; i < 4; ++i) {
            const int id = wave * 4 + i;          // 8 waves x 4 = 32 frags
            const int l  = id >> 3;
            const int mt = (id >> 2) & 1;
            const int ks = id & 3;
            const float* src = Ws[l] + (mt * 32 + col) * 64 + ks * 16 + h1 * 8;
            f32x4 lo = *(const f32x4a*)src;
            f32x4 hi = *(const f32x4a*)(src + 4);
            bf16x8 f;
            f[0] = (__bf16)lo[0]; f[1] = (__bf16)lo[1];
            f[2] = (__bf16)lo[2]; f[3] = (__bf16)lo[3];
            f[4] = (__bf16)hi[0]; f[5] = (__bf16)hi[1];
            f[6] = (__bf16)hi[2]; f[7] = (__bf16)hi[3];
            *(bf16x8a*)&WF[id * 512 + lane * 8] = f;
        }
    }
    __syncthreads();

    // ---- per-lane hoisted constants
    // layer-1 A-frags: k=0..6 -> W1 cols, k=7 -> bias (h1 half zeroed)
    bf16x8 a1[2];
    #pragma unroll
    for (int mt = 0; mt < 2; ++mt) {
        const int o = mt * 32 + col;
        bf16x8 f;
        #pragma unroll
        for (int j = 0; j < 7; ++j)
            f[j] = (__bf16)(hm * w1[o * 7 + j]);
        f[7] = (__bf16)(hm * b1[o]);
        a1[mt] = f;
    }
    // bias scalars for L2..L5 (bf16)
    const float* Bs[4] = {b2, b3, b4, b5};
    __bf16 bb[4][2];
    #pragma unroll
    for (int l = 0; l < 4; ++l)
        #pragma unroll
        for (int mt = 0; mt < 2; ++mt)
            bb[l][mt] = (__bf16)(Bs[l][mt * 32 + col]);
    // ones-B frag: k=0 row = 1
    bf16x8 Bones;
    #pragma unroll
    for (int j = 0; j < 8; ++j) Bones[j] = (__bf16)0.0f;
    Bones[0] = (__bf16)hm;
    // bpermute address: partner lane^32
    const int xaddr = (lane ^ 32) << 2;

    const float cx = coords[2 * bn + 0];
    const float cy = coords[2 * bn + 1];
    const float* img = image + b * 3072;

    f32x16 pool[2];
    pool[0] = zero16(); pool[1] = zero16();

    #pragma unroll 1
    for (int t = 0; t < 4; ++t) {           // 4 passes x 32 px per wave
        const int px = wave * 128 + t * 32 + col;

        // ======== layer 1: K=16 (7 feats + bias row), h1 half zero ========
        bf16x8 bft;
        bft[0] = (__bf16)(hm * img[px]);
        bft[1] = (__bf16)(hm * img[1024 + px]);
        bft[2] = (__bf16)(hm * img[2048 + px]);
        bft[3] = (__bf16)(hm * (float)(px >> 5) * (1.0f / 31.0f));
        bft[4] = (__bf16)(hm * (float)(px & 31) * (1.0f / 31.0f));
        bft[5] = (__bf16)(hm * cx);
        bft[6] = (__bf16)(hm * cy);
        bft[7] = (__bf16)hm;                 // bias row = 1
        f32x16 acc0 = MFMA32(a1[0], bft, zero16());
        f32x16 acc1 = MFMA32(a1[1], bft, zero16());

        // ======== layers 2..5 ========
        #pragma unroll
        for (int l = 0; l < 4; ++l) {
            // ---- transform acc (C layout) -> B-frags, in registers
            u32 d[2][8];
            #pragma unroll
            for (int i = 0; i < 8; ++i) {
                d[0][i] = pk2(lrelu(acc0[2 * i]), lrelu(acc0[2 * i + 1]));
                d[1][i] = pk2(lrelu(acc1[2 * i]), lrelu(acc1[2 * i + 1]));
            }
            u32 Bd[4][4];
            #pragma unroll
            for (int ks = 0; ks < 4; ++ks) {
                const int mt = ks >> 1;
                const int b2i = (ks & 1) * 4;
                const u32 lo0 = d[mt][b2i + 0], lo1 = d[mt][b2i + 1];
                const u32 hi0 = d[mt][b2i + 2], hi1 = d[mt][b2i + 3];
                const u32 s0 = h1 ? lo0 : hi0;
                const u32 s1 = h1 ? lo1 : hi1;
                const u32 r0 = (u32)__builtin_amdgcn_ds_bpermute(xaddr, (int)s0);
                const u32 r1 = (u32)__builtin_amdgcn_ds_bpermute(xaddr, (int)s1);
                Bd[ks][0] = h1 ? r0 : lo0;
                Bd[ks][1] = h1 ? r1 : lo1;
                Bd[ks][2] = h1 ? hi0 : r0;
                Bd[ks][3] = h1 ? hi1 : r1;
            }
            // ---- bias-outer init + 8 GEMM MFMAs
            bf16x8 bA0, bA1;
            #pragma unroll
            for (int j = 0; j < 8; ++j) { bA0[j] = (__bf16)0.0f; bA1[j] = (__bf16)0.0f; }
            bA0[0] = h1 ? (__bf16)0.0f : bb[l][0];
            bA1[0] = h1 ? (__bf16)0.0f : bb[l][1];
            acc0 = MFMA32(bA0, Bones, zero16());
            acc1 = MFMA32(bA1, Bones, zero16());
            #pragma unroll
            for (int ks = 0; ks < 4; ++ks) {
                u32x4 bd = {Bd[ks][0], Bd[ks][1], Bd[ks][2], Bd[ks][3]};
                bf16x8 Bf = __builtin_bit_cast(bf16x8, bd);
                bf16x8 af0 = *(const bf16x8a*)&WF[(l * 8 + 0 + ks) * 512 + lane * 8];
                bf16x8 af1 = *(const bf16x8a*)&WF[(l * 8 + 4 + ks) * 512 + lane * 8];
                acc0 = MFMA32(af0, Bf, acc0);
                acc1 = MFMA32(af1, Bf, acc1);
            }
        }

        // ---- L5 output: leaky + pool accumulate (C layout, registers)
        #pragma unroll
        for (int r = 0; r < 16; ++r) {
            pool[0][r] += lrelu(acc0[r]);
            pool[1][r] += lrelu(acc1[r]);
        }
    }

    // ---- flush pool: ch = 32mt + (r&3) + 8(r>>2) + 4h1, col slot
    #pragma unroll
    for (int mt = 0; mt < 2; ++mt)
        #pragma unroll
        for (int r = 0; r < 16; ++r) {
            const int ch = 32 * mt + (r & 3) + 8 * (r >> 2) + 4 * h1;
            atomicAdd(&PO[ch * 36 + col], pool[mt][r]);
        }
    __syncthreads();

    // ---- head: 64 threads, one channel each
    if (tid < 64) {
        const int c = tid;
        float s = 0.0f;
        #pragma unroll
        for (int k = 0; k < 8; ++k) {
            f32x4 v = *(const f32x4a*)&PO[c * 36 + 4 * k];
            s += v[0] + v[1] + v[2] + v[3];
        }
        const float p = s * (1.0f / 1024.0f);
        float s0 = wl[c] * p;
        float s1 = wl[64 + c] * p;
        float s2 = wl[128 + c] * p;
        #pragma unroll
        for (int off = 32; off > 0; off >>= 1) {
            s0 += __shfl_down(s0, off, 64);
            s1 += __shfl_down(s1, off, 64);
            s2 += __shfl_down(s2, off, 64);
        }
        if (c == 0) {
            const int n = bn & 127;
            out[(b * 3 + 0) * 128 + n] = 1.0f / (1.0f + expf(-(bl[0] + s0)));
            out[(b * 3 + 1) * 128 + n] = 1.0f / (1.0f + expf(-(bl[1] + s1)));
            out[(b * 3 + 2) * 128 + n] = 1.0f / (1.0f + expf(-(bl[2] + s2)));
        }
    }
}

extern "C" void kernel_launch(void* const* d_in, const int* in_sizes, int n_in,
                              void* d_out, int out_size, void* d_ws, size_t ws_size,
                              hipStream_t stream) {
    const float* image  = (const float*)d_in[0];
    const float* coords = (const float*)d_in[1];
    const float* w1 = (const float*)d_in[2];
    const float* b1 = (const float*)d_in[3];
    const float* w2 = (const float*)d_in[4];
    const float* b2 = (const float*)d_in[5];
    const float* w3 = (const float*)d_in[6];
    const float* b3 = (const float*)d_in[7];
    const float* w4 = (const float*)d_in[8];
    const float* b4 = (const float*)d_in[9];
    const float* w5 = (const float*)d_in[10];
    const float* b5 = (const float*)d_in[11];
    const float* wl = (const float*)d_in[12];
    const float* bl = (const float*)d_in[13];
    float* out = (float*)d_out;

    mlp_mfma_kernel<<<dim3(512), dim3(512), 0, stream>>>(
        image, coords, w1, b1, w2, b2, w3, b3, w4, b4, w5, b5, wl, bl, out);
}

// Round 12
// 109.854 us; speedup vs baseline: 1.4507x; 1.4507x over previous
//
#include <hip/hip_runtime.h>
#include <math.h>

// B=4, N=128, H=W=32, C=64.  out[b][j][n] = sigmoid(wl[j,:] . mean_hw MLP(...) + bl[j])
//
// MFMA: layers 2..5 are 64x64 GEMMs over pixel columns (16x16x32_bf16,
// M=64ch x N=16px per MFMA); layer 1 (7->64) K=32 zero-padded.
// Weights staged once per block into LDS, lane-major -> ds_read_b128.
//
// R12: af REGISTER DOUBLE-BUFFER on the R8 base. Post-mortems R9-R11: the
// 128-arch-VGPR wall is absolute (attr/pin/asm all failed; R11's register-act
// structure spilled invisibly to L2 and ran 2.3x slower). R8's remaining
// exposed latency: each layer's 8 af ds_read_b128 sit on the layer-entry
// critical path (in-order lgkm: MFMA's bf-wait drains af too). Fix: rotate
// af through regs — layer l+1's af loads issue after layer l's g1 bf reads
// (so g1's MFMA lgkm wait excludes them) and complete under g1 MFMA+stores;
// l=3 wraps to layer 0 for the next t. Dropped R8's pix prefetch to fund
// the +32-reg afn buffer (~120 projected vs 128 wall; R8 base measured 88).
// Tripwires: VGPR<=128, WRITE_SIZE ~48B (else spill -> revert to R8).
// Act transform C->B via wave-private LDS (no barriers in main loop):
//   C: col=lane&15, row=(lane>>4)*4+reg   [m89-verified]
//   A/B: n=lane&15, k=(lane>>4)*8+j        [m120-verified]

typedef float  f32x4  __attribute__((ext_vector_type(4)));
typedef f32x4  f32x4a __attribute__((may_alias));
typedef __bf16 bf16x8 __attribute__((ext_vector_type(8)));
typedef bf16x8 bf16x8a __attribute__((may_alias));
typedef __bf16 bf16x4 __attribute__((ext_vector_type(4)));
typedef bf16x4 bf16x4a __attribute__((may_alias));
typedef float  floata __attribute__((may_alias));

#define MFMA16(a, b, c) __builtin_amdgcn_mfma_f32_16x16x32_bf16((a), (b), (c), 0, 0, 0)

// LDS halfword offsets
#define WL_H    0            // 36 frag-groups x 512 halfwords (36864 B)
#define ACT_H   18432        // 4 waves x 4096 halfwords (32768 B)

__global__ __launch_bounds__(256, 2) void mlp_mfma_kernel(
    const float* __restrict__ image,   // [4,3,32,32]
    const float* __restrict__ coords,  // [4,128,2]
    const float* __restrict__ w1, const float* __restrict__ b1,   // [64,7],[64]
    const float* __restrict__ w2, const float* __restrict__ b2,   // [64,64],[64]
    const float* __restrict__ w3, const float* __restrict__ b3,
    const float* __restrict__ w4, const float* __restrict__ b4,
    const float* __restrict__ w5, const float* __restrict__ b5,
    const float* __restrict__ wl, const float* __restrict__ bl,   // [3,64],[3]
    float* __restrict__ out)           // [4,3,128]
{
    __shared__ __align__(16) __bf16 LDSH[18432 + 16384];  // weights + acts
    __shared__ __align__(16) float  BL[320];              // biases [5][64]

    const int tid  = threadIdx.x;
    const int wave = tid >> 6;
    const int lane = tid & 63;
    const int c15  = lane & 15;
    const int q    = lane >> 4;
    const int bn   = blockIdx.x;
    const int b    = bn >> 7;

    const float qm = (q == 0) ? 1.0f : 0.0f;   // layer-1 K=32 zero-pad mask

    const float* Ws[4] = {w2, w3, w4, w5};

    // ---- stage weight A-frags into LDS, lane-major: frag id*512h + lane*8h
    //   id = l*8 + mt*2 + ks  (l=0..3 -> w2..w5), id = 32+mt -> w1
    #pragma unroll 1
    for (int i = 0; i < 9; ++i) {
        const int id = wave + i * 4;           // 4 waves cover 0..35
        __bf16* dst = &LDSH[WL_H + id * 512 + lane * 8];
        if (id < 32) {
            const int l  = id >> 3;
            const int mt = (id >> 1) & 3;
            const int ks = id & 1;
            const float* src = Ws[l] + (mt * 16 + c15) * 64 + ks * 32 + q * 8;
            f32x4 lo = *(const f32x4a*)src;
            f32x4 hi = *(const f32x4a*)(src + 4);
            bf16x8 f;
            f[0] = (__bf16)lo[0]; f[1] = (__bf16)lo[1];
            f[2] = (__bf16)lo[2]; f[3] = (__bf16)lo[3];
            f[4] = (__bf16)hi[0]; f[5] = (__bf16)hi[1];
            f[6] = (__bf16)hi[2]; f[7] = (__bf16)hi[3];
            *(bf16x8a*)dst = f;
        } else {
            const int mt = id - 32;
            bf16x8 f;
            #pragma unroll
            for (int j = 0; j < 7; ++j)
                f[j] = (__bf16)(qm * w1[(mt * 16 + c15) * 7 + j]);
            f[7] = (__bf16)0.0f;
            *(bf16x8a*)dst = f;
        }
    }
    if (tid < 64) {
        BL[tid]       = b1[tid];
        BL[64 + tid]  = b2[tid];
        BL[128 + tid] = b3[tid];
        BL[192 + tid] = b4[tid];
        BL[256 + tid] = b5[tid];
    }
    __syncthreads();

    // ---- hoisted: layer-1 A-frags in registers (loop-invariant)
    bf16x8 a1[4];
    #pragma unroll
    for (int mt = 0; mt < 4; ++mt)
        a1[mt] = *(const bf16x8a*)&LDSH[WL_H + (32 + mt) * 512 + lane * 8];

    // ---- af double-buffer: current layer's A-frags in registers
    bf16x8 afc[4][2];
    #pragma unroll
    for (int mt = 0; mt < 4; ++mt)
        #pragma unroll
        for (int ks = 0; ks < 2; ++ks)
            afc[mt][ks] = *(const bf16x8a*)
                &LDSH[WL_H + (mt * 2 + ks) * 512 + lane * 8];   // layer 0 (=w2)

    const float cx = coords[2 * bn + 0];
    const float cy = coords[2 * bn + 1];
    const float* img = image + b * 3072;

    __bf16* Xw = &LDSH[ACT_H + wave * 4096];   // 2 tiles x 2048 halfwords
    const int lane_woff = c15 * 8 + (q >> 1) * 128 + (q & 1) * 4;

    f32x4 pool[4];
    #pragma unroll
    for (int mt = 0; mt < 4; ++mt) pool[mt] = (f32x4){0.f, 0.f, 0.f, 0.f};

    // leaky + cvt + C->B transform of one 32-px tile into its act region
    auto store_tile = [&](f32x4 (&acc)[4][2], int g) {
        #pragma unroll
        for (int mt = 0; mt < 4; ++mt)
            #pragma unroll
            for (int ntl = 0; ntl < 2; ++ntl) {
                f32x4 a = acc[mt][ntl];
                bf16x4 p;
                #pragma unroll
                for (int r = 0; r < 4; ++r) {
                    float v = fmaxf(a[r], 0.1f * a[r]);
                    p[r] = (__bf16)v;
                }
                const int off = g * 2048 + (ntl * 2 + (mt >> 1)) * 512
                              + (mt & 1) * 256 + lane_woff;
                *(bf16x4a*)&Xw[off] = p;
            }
    };

    #pragma unroll 1
    for (int t = 0; t < 4; ++t) {           // 4 passes x 64 px (2 tiles)
        // ======== layer 1 ========
        {
            f32x4 bv[4];
            #pragma unroll
            for (int mt = 0; mt < 4; ++mt)
                bv[mt] = *(const f32x4a*)&BL[mt * 16 + 4 * q];

            #pragma unroll
            for (int g = 0; g < 2; ++g) {
                bf16x8 bft[2];
                #pragma unroll
                for (int ntl = 0; ntl < 2; ++ntl) {
                    const int hw = wave * 256 + t * 64 + g * 32 + ntl * 16 + c15;
                    const float i0 = img[hw];
                    const float i1 = img[1024 + hw];
                    const float i2 = img[2048 + hw];
                    bf16x8 f;
                    f[0] = (__bf16)(qm * i0);
                    f[1] = (__bf16)(qm * i1);
                    f[2] = (__bf16)(qm * i2);
                    f[3] = (__bf16)(qm * (float)(hw >> 5) * (1.0f / 31.0f));
                    f[4] = (__bf16)(qm * (float)(hw & 31) * (1.0f / 31.0f));
                    f[5] = (__bf16)(qm * cx);
                    f[6] = (__bf16)(qm * cy);
                    f[7] = (__bf16)0.0f;
                    bft[ntl] = f;
                }
                f32x4 acc[4][2];
                #pragma unroll
                for (int mt = 0; mt < 4; ++mt) {
                    acc[mt][0] = bv[mt]; acc[mt][1] = bv[mt];
                }
                #pragma unroll
                for (int mt = 0; mt < 4; ++mt)
                    #pragma unroll
                    for (int ntl = 0; ntl < 2; ++ntl)
                        acc[mt][ntl] = MFMA16(a1[mt], bft[ntl], acc[mt][ntl]);
                store_tile(acc, g);
            }
        }

        // ======== layers 2..5 — unrolled; af in regs, next-layer prefetch ==
        #pragma unroll
        for (int l = 0; l < 4; ++l) {
            bf16x8 afn[4][2];   // next layer's frags ((l+1)&3 -> wraps to w2)
            f32x4 bv[4];
            #pragma unroll
            for (int mt = 0; mt < 4; ++mt)
                bv[mt] = *(const f32x4a*)&BL[(l + 1) * 64 + mt * 16 + 4 * q];

            #pragma unroll
            for (int g = 0; g < 2; ++g) {
                bf16x8 bf[2][2];
                #pragma unroll
                for (int ntl = 0; ntl < 2; ++ntl)
                    #pragma unroll
                    for (int ks = 0; ks < 2; ++ks)
                        bf[ntl][ks] = *(const bf16x8a*)
                            &Xw[g * 2048 + ((ntl * 2 + ks) * 64 + lane) * 8];
                if (g == 1) {
                    // prefetch AFTER g1's bf reads (g1's MFMA lgkm wait
                    // excludes these), covered by g1 MFMA + store window
                    const int ln = (l + 1) & 3;
                    #pragma unroll
                    for (int mt = 0; mt < 4; ++mt)
                        #pragma unroll
                        for (int ks = 0; ks < 2; ++ks)
                            afn[mt][ks] = *(const bf16x8a*)
                                &LDSH[WL_H + (ln * 8 + mt * 2 + ks) * 512 + lane * 8];
                }
                f32x4 acc[4][2];
                #pragma unroll
                for (int mt = 0; mt < 4; ++mt) {
                    acc[mt][0] = bv[mt]; acc[mt][1] = bv[mt];
                }
                #pragma unroll
                for (int mt = 0; mt < 4; ++mt)
                    #pragma unroll
                    for (int ntl = 0; ntl < 2; ++ntl)
                        #pragma unroll
                        for (int ks = 0; ks < 2; ++ks)
                            acc[mt][ntl] = MFMA16(afc[mt][ks], bf[ntl][ks], acc[mt][ntl]);
                if (l < 3) {
                    store_tile(acc, g);
                } else {
                    #pragma unroll
                    for (int mt = 0; mt < 4; ++mt)
                        #pragma unroll
                        for (int ntl = 0; ntl < 2; ++ntl) {
                            f32x4 a = acc[mt][ntl];
                            #pragma unroll
                            for (int r = 0; r < 4; ++r)
                                pool[mt][r] += fmaxf(a[r], 0.1f * a[r]);
                        }
                }
            }
            // rotate double-buffer
            #pragma unroll
            for (int mt = 0; mt < 4; ++mt)
                #pragma unroll
                for (int ks = 0; ks < 2; ++ks)
                    afc[mt][ks] = afn[mt][ks];
        }
    }

    // ---- pool partials -> float view of this wave's act region: [ch][col16]
    floata* Xf = (floata*)Xw;
    #pragma unroll
    for (int mt = 0; mt < 4; ++mt)
        #pragma unroll
        for (int r = 0; r < 4; ++r)
            Xf[(mt * 16 + 4 * q + r) * 16 + c15] = pool[mt][r];

    __syncthreads();

    // ---- block reduce (4 waves x 16 cols) + head + sigmoid
    if (tid < 64) {
        const int c = tid;
        float s = 0.0f;
        #pragma unroll
        for (int w = 0; w < 4; ++w) {
            const floata* P = (const floata*)&LDSH[ACT_H + w * 4096];
            #pragma unroll
            for (int c4 = 0; c4 < 4; ++c4) {
                f32x4 v = *(const f32x4a*)&P[c * 16 + c4 * 4];
                s += v[0] + v[1] + v[2] + v[3];
            }
        }
        const float p = s * (1.0f / 1024.0f);
        float s0 = wl[c] * p;
        float s1 = wl[64 + c] * p;
        float s2 = wl[128 + c] * p;
        #pragma unroll
        for (int off = 32; off > 0; off >>= 1) {
            s0 += __shfl_down(s0, off, 64);
            s1 += __shfl_down(s1, off, 64);
            s2 += __shfl_down(s2, off, 64);
        }
        if (c == 0) {
            const int n = bn & 127;
            out[(b * 3 + 0) * 128 + n] = 1.0f / (1.0f + expf(-(bl[0] + s0)));
            out[(b * 3 + 1) * 128 + n] = 1.0f / (1.0f + expf(-(bl[1] + s1)));
            out[(b * 3 + 2) * 128 + n] = 1.0f / (1.0f + expf(-(bl[2] + s2)));
        }
    }
}

extern "C" void kernel_launch(void* const* d_in, const int* in_sizes, int n_in,
                              void* d_out, int out_size, void* d_ws, size_t ws_size,
                              hipStream_t stream) {
    const float* image  = (const float*)d_in[0];
    const float* coords = (const float*)d_in[1];
    const float* w1 = (const float*)d_in[2];
    const float* b1 = (const float*)d_in[3];
    const float* w2 = (const float*)d_in[4];
    const float* b2 = (const float*)d_in[5];
    const float* w3 = (const float*)d_in[6];
    const float* b3 = (const float*)d_in[7];
    const float* w4 = (const float*)d_in[8];
    const float* b4 = (const float*)d_in[9];
    const float* w5 = (const float*)d_in[10];
    const float* b5 = (const float*)d_in[11];
    const float* wl = (const float*)d_in[12];
    const float* bl = (const float*)d_in[13];
    float* out = (float*)d_out;

    mlp_mfma_kernel<<<dim3(512), dim3(256), 0, stream>>>(
        image, coords, w1, b1, w2, b2, w3, b3, w4, b4, w5, b5, wl, bl, out);
}